// Round 1
// baseline (723.887 us; speedup 1.0000x reference)
//
#include <hip/hip_runtime.h>
#include <stdint.h>

typedef unsigned short u16;
typedef unsigned int   u32;
typedef __bf16 bf16_t;
typedef bf16_t bf16x4 __attribute__((ext_vector_type(4)));
typedef bf16_t bf16x8 __attribute__((ext_vector_type(8)));
typedef float  f32x4  __attribute__((ext_vector_type(4)));
typedef u16    u16x8  __attribute__((ext_vector_type(8)));

#define BB 2
#define NN 2048
#define CC 2048
#define HH 16
#define DD 128
#define FF 6144
#define MM 4096

__device__ __forceinline__ u16 f2bf(float f){
    u32 u = __builtin_bit_cast(u32, f);
    u32 r = (u + 0x7fffu + ((u >> 16) & 1u)) >> 16;
    return (u16)r;
}
__device__ __forceinline__ float bf2f(u16 h){
    u32 u = ((u32)h) << 16;
    return __builtin_bit_cast(float, u);
}
__device__ __forceinline__ f32x4 MFMA(bf16x8 a, bf16x8 b, f32x4 c){
    return __builtin_amdgcn_mfma_f32_16x16x32_bf16(a, b, c, 0, 0, 0);
}

// ---------------- conversion kernels ----------------
__global__ void k_split_x(const float* __restrict__ x, u16* __restrict__ xhi,
                          u16* __restrict__ xlo, int n4){
    int i = blockIdx.x * blockDim.x + threadIdx.x;
    int stride = gridDim.x * blockDim.x;
    for (; i < n4; i += stride){
        float4 v = ((const float4*)x)[i];
        u16 h0 = f2bf(v.x), h1 = f2bf(v.y), h2 = f2bf(v.z), h3 = f2bf(v.w);
        ushort4 hi; hi.x = h0; hi.y = h1; hi.z = h2; hi.w = h3;
        ushort4 lo;
        lo.x = f2bf(v.x - bf2f(h0));
        lo.y = f2bf(v.y - bf2f(h1));
        lo.z = f2bf(v.z - bf2f(h2));
        lo.w = f2bf(v.w - bf2f(h3));
        ((ushort4*)xhi)[i] = hi;
        ((ushort4*)xlo)[i] = lo;
    }
}

__global__ void k_f2bf(const float* __restrict__ a, u16* __restrict__ o, int n4){
    int i = blockIdx.x * blockDim.x + threadIdx.x;
    int stride = gridDim.x * blockDim.x;
    for (; i < n4; i += stride){
        float4 v = ((const float4*)a)[i];
        ushort4 r; r.x = f2bf(v.x); r.y = f2bf(v.y); r.z = f2bf(v.z); r.w = f2bf(v.w);
        ((ushort4*)o)[i] = r;
    }
}

// ---------------- GEMM:  out[m][n] = sum_k A[m][k] * Bw[n][k]  ----------------
// SPLIT: A2 is a low-order bf16 correction of A (acc += A2*Bw too)
// OUTBF: write bf16 (u16) else fp32 + bias
template<int SPLIT, int OUTBF>
__global__ __launch_bounds__(256) void k_gemm_bt(
    const u16* __restrict__ A, const u16* __restrict__ A2,
    const u16* __restrict__ Bw, float* __restrict__ outf, u16* __restrict__ outb,
    const float* __restrict__ bias, int M, int N, int K)
{
    __shared__ u16 As[128 * 32];
    __shared__ u16 Bs[128 * 32];
    const int tid  = threadIdx.x;
    const int brow = blockIdx.y * 128;
    const int bcol = blockIdx.x * 128;
    const int w = tid >> 6, lane = tid & 63;
    const int wr = w >> 1, wc = w & 1;
    const int l15 = lane & 15, g = lane >> 4;

    f32x4 acc[4][4];
    #pragma unroll
    for (int i = 0; i < 4; i++)
        #pragma unroll
        for (int j = 0; j < 4; j++){
            f32x4 z = {0.f, 0.f, 0.f, 0.f};
            acc[i][j] = z;
        }

    for (int k0 = 0; k0 < K; k0 += 32){
        __syncthreads();
        #pragma unroll
        for (int it = 0; it < 2; ++it){
            int idx = it * 2048 + tid * 8;
            int r = idx >> 5, c = idx & 31;
            *(uint4*)&Bs[idx] = *(const uint4*)&Bw[(size_t)(bcol + r) * K + k0 + c];
            *(uint4*)&As[idx] = *(const uint4*)&A [(size_t)(brow + r) * K + k0 + c];
        }
        __syncthreads();
        bf16x8 fb[4];
        #pragma unroll
        for (int j = 0; j < 4; j++){
            int row = wc * 64 + j * 16 + l15;
            fb[j] = *(const bf16x8*)&Bs[row * 32 + 8 * g];
        }
        #pragma unroll
        for (int i = 0; i < 4; i++){
            int row = wr * 64 + i * 16 + l15;
            bf16x8 fa = *(const bf16x8*)&As[row * 32 + 8 * g];
            #pragma unroll
            for (int j = 0; j < 4; j++) acc[i][j] = MFMA(fa, fb[j], acc[i][j]);
        }
        if (SPLIT){
            __syncthreads();
            #pragma unroll
            for (int it = 0; it < 2; ++it){
                int idx = it * 2048 + tid * 8;
                int r = idx >> 5, c = idx & 31;
                *(uint4*)&As[idx] = *(const uint4*)&A2[(size_t)(brow + r) * K + k0 + c];
            }
            __syncthreads();
            #pragma unroll
            for (int i = 0; i < 4; i++){
                int row = wr * 64 + i * 16 + l15;
                bf16x8 fa = *(const bf16x8*)&As[row * 32 + 8 * g];
                #pragma unroll
                for (int j = 0; j < 4; j++) acc[i][j] = MFMA(fa, fb[j], acc[i][j]);
            }
        }
    }

    #pragma unroll
    for (int i = 0; i < 4; i++){
        #pragma unroll
        for (int j = 0; j < 4; j++){
            int colg = bcol + wc * 64 + j * 16 + l15;
            #pragma unroll
            for (int r = 0; r < 4; r++){
                int rowg = brow + wr * 64 + i * 16 + 4 * g + r;
                float v = acc[i][j][r];
                if (OUTBF) outb[(size_t)rowg * N + colg] = f2bf(v);
                else       outf[(size_t)rowg * N + colg] = v + bias[colg];
            }
        }
    }
}

// ---------------- RMSNorm + RoPE + transpose to (B,H,N,D) ----------------
__global__ __launch_bounds__(256) void k_norm_rope(
    const u16* __restrict__ qkv, const float* __restrict__ qw, const float* __restrict__ kw,
    const float* __restrict__ cosb, const float* __restrict__ sinb,
    u16* __restrict__ qout, u16* __restrict__ kout, u16* __restrict__ vout)
{
    const int m = blockIdx.x;           // 0..4095  (b*N + n)
    const int b = m >> 11;
    const int n = m & 2047;
    const int t = threadIdx.x;
    const size_t base = (size_t)m * FF;
    const int e0 = t * 8;

    float qv[8], kvv[8];
    uint4 qa = *(const uint4*)&qkv[base + e0];
    uint4 ka = *(const uint4*)&qkv[base + CC + e0];
    uint4 va = *(const uint4*)&qkv[base + 2 * CC + e0];
    {
        u32 aa[4] = {qa.x, qa.y, qa.z, qa.w};
        u32 bb[4] = {ka.x, ka.y, ka.z, ka.w};
        #pragma unroll
        for (int i = 0; i < 4; i++){
            qv[2*i]   = bf2f((u16)(aa[i] & 0xffff));
            qv[2*i+1] = bf2f((u16)(aa[i] >> 16));
            kvv[2*i]   = bf2f((u16)(bb[i] & 0xffff));
            kvv[2*i+1] = bf2f((u16)(bb[i] >> 16));
        }
    }
    float sq = 0.f, sk = 0.f;
    #pragma unroll
    for (int i = 0; i < 8; i++){ sq += qv[i]*qv[i]; sk += kvv[i]*kvv[i]; }
    #pragma unroll
    for (int o = 32; o > 0; o >>= 1){ sq += __shfl_xor(sq, o); sk += __shfl_xor(sk, o); }
    __shared__ float red[8];
    if ((t & 63) == 0){ red[(t >> 6)*2] = sq; red[(t >> 6)*2 + 1] = sk; }
    __syncthreads();
    sq = red[0] + red[2] + red[4] + red[6];
    sk = red[1] + red[3] + red[5] + red[7];
    const float rq = rsqrtf(sq * (1.f / 2048.f) + 1e-5f);
    const float rk = rsqrtf(sk * (1.f / 2048.f) + 1e-5f);

    const int h  = t >> 4;
    const int d0 = (t & 15) * 8;
    const float* cp = cosb + (size_t)n * DD + d0;
    const float* sp = sinb + (size_t)n * DD + d0;
    float qo[8], ko[8];
    #pragma unroll
    for (int j = 0; j < 8; j += 2){
        float c0 = cp[j], c1 = cp[j+1], s0 = sp[j], s1 = sp[j+1];
        float x0 = qv[j]   * rq * qw[e0 + j];
        float x1 = qv[j+1] * rq * qw[e0 + j + 1];
        qo[j]   = x0 * c0 - x1 * s0;
        qo[j+1] = x1 * c1 + x0 * s1;
        float y0 = kvv[j]   * rk * kw[e0 + j];
        float y1 = kvv[j+1] * rk * kw[e0 + j + 1];
        ko[j]   = y0 * c0 - y1 * s0;
        ko[j+1] = y1 * c1 + y0 * s1;
    }
    const size_t obase = ((size_t)(b * HH + h) * NN + n) * DD + d0;
    uint4 pq, pk;
    pq.x = (u32)f2bf(qo[0]) | ((u32)f2bf(qo[1]) << 16);
    pq.y = (u32)f2bf(qo[2]) | ((u32)f2bf(qo[3]) << 16);
    pq.z = (u32)f2bf(qo[4]) | ((u32)f2bf(qo[5]) << 16);
    pq.w = (u32)f2bf(qo[6]) | ((u32)f2bf(qo[7]) << 16);
    pk.x = (u32)f2bf(ko[0]) | ((u32)f2bf(ko[1]) << 16);
    pk.y = (u32)f2bf(ko[2]) | ((u32)f2bf(ko[3]) << 16);
    pk.z = (u32)f2bf(ko[4]) | ((u32)f2bf(ko[5]) << 16);
    pk.w = (u32)f2bf(ko[6]) | ((u32)f2bf(ko[7]) << 16);
    *(uint4*)&qout[obase] = pq;
    *(uint4*)&kout[obase] = pk;
    *(uint4*)&vout[obase] = va;   // v: pass-through (already bf16)
}

// ---------------- attention: one wave per (b,h,16 q-rows) ----------------
__global__ __launch_bounds__(64) void k_attn(
    const u16* __restrict__ Q, const u16* __restrict__ Kt, const u16* __restrict__ Vt,
    u16* __restrict__ O)
{
    const int qt = blockIdx.x;          // 0..127
    const int h  = blockIdx.y;          // 0..15
    const int b  = blockIdx.z;          // 0..1
    const int lane = threadIdx.x;
    const int l15 = lane & 15, g = lane >> 4;
    const size_t hb = (size_t)(b * HH + h) * NN * DD;
    const int qbase = qt * 16;
    const float sc = 0.08838834764831845f * 1.4426950408889634f; // D^-0.5 * log2(e)

    // Q fragments (B operand of S^T = K * Q^T):  col = qi = l15, k=d = 32c+8g+j
    bf16x8 qf[4];
    {
        const u16* qrow = Q + hb + (size_t)(qbase + l15) * DD;
        #pragma unroll
        for (int c = 0; c < 4; c++)
            qf[c] = *(const bf16x8*)(qrow + c * 32 + 8 * g);
    }

    f32x4 oacc[8];
    #pragma unroll
    for (int tb = 0; tb < 8; tb++){ f32x4 z = {0.f,0.f,0.f,0.f}; oacc[tb] = z; }
    float lsum = 0.f;

    // kj-interleaved row permutation: tile0 takes kj = 8*(m>>2)+(m&3), tile1 = +4,
    // so lane's C-regs line up exactly with the contiguous-8 A-fragment of P.
    const int mperm = 8 * (l15 >> 2) + (l15 & 3);

    for (int kv0 = 0; kv0 < NN; kv0 += 32){
        f32x4 st0 = {0.f,0.f,0.f,0.f}, st1 = {0.f,0.f,0.f,0.f};
        const u16* k0row = Kt + hb + (size_t)(kv0 + mperm) * DD;
        const u16* k1row = k0row + 4 * DD;
        #pragma unroll
        for (int c = 0; c < 4; c++){
            bf16x8 kf0 = *(const bf16x8*)(k0row + c * 32 + 8 * g);
            bf16x8 kf1 = *(const bf16x8*)(k1row + c * 32 + 8 * g);
            st0 = MFMA(kf0, qf[c], st0);
            st1 = MFMA(kf1, qf[c], st1);
        }
        // P = exp(S*scale); lane holds S[qi=l15][kj = kv0 + 8g + {0..3 from st0, 4..7 from st1}]
        u16x8 pu;
        #pragma unroll
        for (int r = 0; r < 4; r++){
            u16 b0 = f2bf(exp2f(st0[r] * sc));
            u16 b1 = f2bf(exp2f(st1[r] * sc));
            pu[r]     = b0;
            pu[r + 4] = b1;
            lsum += bf2f(b0) + bf2f(b1);
        }
        bf16x8 pf = __builtin_bit_cast(bf16x8, pu);
        // V fragments + PV
        #pragma unroll
        for (int tb = 0; tb < 8; tb++){
            const u16* vcol = Vt + hb + (size_t)kv0 * DD + tb * 16 + l15;
            u16x8 vu;
            #pragma unroll
            for (int j = 0; j < 8; j++)
                vu[j] = vcol[(size_t)(8 * g + j) * DD];
            bf16x8 vf = __builtin_bit_cast(bf16x8, vu);
            oacc[tb] = MFMA(pf, vf, oacc[tb]);
        }
    }

    // row sums: lane's partial covers kj = 8g..8g+7 over all tiles; reduce over g
    lsum += __shfl_xor(lsum, 16);
    lsum += __shfl_xor(lsum, 32);
    float linv = 1.f / lsum;            // valid for q-row l15 on every lane
    float li[4];
    #pragma unroll
    for (int r = 0; r < 4; r++) li[r] = __shfl(linv, 4 * g + r);

    // O C-layout: row qi = 4g+r, col d = 16*tb + l15;  write (B,N,C) bf16
    #pragma unroll
    for (int tb = 0; tb < 8; tb++){
        #pragma unroll
        for (int r = 0; r < 4; r++){
            int qi = qbase + 4 * g + r;
            O[(size_t)(b * NN + qi) * CC + h * DD + tb * 16 + l15] = f2bf(oacc[tb][r] * li[r]);
        }
    }
}

// ---------------- launch ----------------
extern "C" void kernel_launch(void* const* d_in, const int* in_sizes, int n_in,
                              void* d_out, int out_size, void* d_ws, size_t ws_size,
                              hipStream_t stream) {
    const float* x      = (const float*)d_in[0];
    const float* w_qkv  = (const float*)d_in[1];
    const float* qw     = (const float*)d_in[2];
    const float* kw     = (const float*)d_in[3];
    const float* cosb   = (const float*)d_in[4];
    const float* sinb   = (const float*)d_in[5];
    const float* w_proj = (const float*)d_in[6];
    const float* b_proj = (const float*)d_in[7];
    float* out = (float*)d_out;

    // workspace layout (bytes, all 256-aligned)
    const size_t sz_xhi  = (size_t)MM * CC * 2;        // 16 MiB
    const size_t sz_wqkv = (size_t)FF * CC * 2;        // 24 MiB
    const size_t sz_wprj = (size_t)CC * CC * 2;        // 8 MiB
    const size_t sz_qkv  = (size_t)MM * FF * 2;        // 48 MiB
    const size_t sz_t    = (size_t)BB * HH * NN * DD * 2; // 16 MiB each
    const size_t need = sz_xhi*2 + sz_wqkv + sz_wprj + sz_qkv + sz_t*3 + sz_xhi;
    if (ws_size < need) return;

    char* ws = (char*)d_ws;
    size_t off = 0;
    auto alloc = [&](size_t bytes){ void* p = ws + off; off += (bytes + 255) & ~(size_t)255; return p; };
    u16* x_hi    = (u16*)alloc(sz_xhi);
    u16* x_lo    = (u16*)alloc(sz_xhi);
    u16* wqkv_bf = (u16*)alloc(sz_wqkv);
    u16* wprj_bf = (u16*)alloc(sz_wprj);
    u16* qkv     = (u16*)alloc(sz_qkv);
    u16* qr      = (u16*)alloc(sz_t);
    u16* kr      = (u16*)alloc(sz_t);
    u16* vt      = (u16*)alloc(sz_t);
    u16* ob      = (u16*)alloc(sz_xhi);

    k_split_x<<<2048, 256, 0, stream>>>(x, x_hi, x_lo, MM * CC / 4);
    k_f2bf<<<2048, 256, 0, stream>>>(w_qkv, wqkv_bf, FF * CC / 4);
    k_f2bf<<<1024, 256, 0, stream>>>(w_proj, wprj_bf, CC * CC / 4);
    k_gemm_bt<1, 1><<<dim3(FF / 128, MM / 128), 256, 0, stream>>>(
        x_hi, x_lo, wqkv_bf, nullptr, qkv, nullptr, MM, FF, CC);
    k_norm_rope<<<MM, 256, 0, stream>>>(qkv, qw, kw, cosb, sinb, qr, kr, vt);
    k_attn<<<dim3(NN / 16, HH, BB), 64, 0, stream>>>(qr, kr, vt, ob);
    k_gemm_bt<0, 0><<<dim3(CC / 128, MM / 128), 256, 0, stream>>>(
        ob, nullptr, wprj_bf, out, nullptr, b_proj, MM, CC, CC);
}

// Round 2
// 557.518 us; speedup vs baseline: 1.2984x; 1.2984x over previous
//
#include <hip/hip_runtime.h>
#include <stdint.h>

typedef unsigned short u16;
typedef unsigned int   u32;
typedef __bf16 bf16_t;
typedef bf16_t bf16x4 __attribute__((ext_vector_type(4)));
typedef bf16_t bf16x8 __attribute__((ext_vector_type(8)));
typedef float  f32x4  __attribute__((ext_vector_type(4)));
typedef u16    u16x8  __attribute__((ext_vector_type(8)));

#define BB 2
#define NN 2048
#define CC 2048
#define HH 16
#define DD 128
#define FF 6144
#define MM 4096

__device__ __forceinline__ u16 f2bf(float f){
    u32 u = __builtin_bit_cast(u32, f);
    u32 r = (u + 0x7fffu + ((u >> 16) & 1u)) >> 16;
    return (u16)r;
}
__device__ __forceinline__ float bf2f(u16 h){
    u32 u = ((u32)h) << 16;
    return __builtin_bit_cast(float, u);
}
__device__ __forceinline__ f32x4 MFMA(bf16x8 a, bf16x8 b, f32x4 c){
    return __builtin_amdgcn_mfma_f32_16x16x32_bf16(a, b, c, 0, 0, 0);
}
__device__ __forceinline__ void gld16(const void* g, void* l){
    __builtin_amdgcn_global_load_lds(
        (const __attribute__((address_space(1))) void*)(g),
        (__attribute__((address_space(3))) void*)(l), 16, 0, 0);
}

// ---------------- conversion kernels ----------------
__global__ void k_split_x(const float* __restrict__ x, u16* __restrict__ xhi,
                          u16* __restrict__ xlo, int n4){
    int i = blockIdx.x * blockDim.x + threadIdx.x;
    int stride = gridDim.x * blockDim.x;
    for (; i < n4; i += stride){
        float4 v = ((const float4*)x)[i];
        u16 h0 = f2bf(v.x), h1 = f2bf(v.y), h2 = f2bf(v.z), h3 = f2bf(v.w);
        ushort4 hi; hi.x = h0; hi.y = h1; hi.z = h2; hi.w = h3;
        ushort4 lo;
        lo.x = f2bf(v.x - bf2f(h0));
        lo.y = f2bf(v.y - bf2f(h1));
        lo.z = f2bf(v.z - bf2f(h2));
        lo.w = f2bf(v.w - bf2f(h3));
        ((ushort4*)xhi)[i] = hi;
        ((ushort4*)xlo)[i] = lo;
    }
}

__global__ void k_f2bf(const float* __restrict__ a, u16* __restrict__ o, int n4){
    int i = blockIdx.x * blockDim.x + threadIdx.x;
    int stride = gridDim.x * blockDim.x;
    for (; i < n4; i += stride){
        float4 v = ((const float4*)a)[i];
        ushort4 r; r.x = f2bf(v.x); r.y = f2bf(v.y); r.z = f2bf(v.z); r.w = f2bf(v.w);
        ((ushort4*)o)[i] = r;
    }
}

// ---------------- GEMM:  out[m][n] = sum_k A[m][k] * Bw[n][k]  ----------------
template<int SPLIT, int OUTBF>
__global__ __launch_bounds__(256) void k_gemm_bt(
    const u16* __restrict__ A, const u16* __restrict__ A2,
    const u16* __restrict__ Bw, float* __restrict__ outf, u16* __restrict__ outb,
    const float* __restrict__ bias, int M, int N, int K)
{
    __shared__ u16 As[128 * 32];
    __shared__ u16 Bs[128 * 32];
    const int tid  = threadIdx.x;
    const int brow = blockIdx.y * 128;
    const int bcol = blockIdx.x * 128;
    const int w = tid >> 6, lane = tid & 63;
    const int wr = w >> 1, wc = w & 1;
    const int l15 = lane & 15, g = lane >> 4;
    // staging geometry: thread stages 16B; rows r/r+64, col c
    const int sr = tid >> 2;            // 0..63
    const int sc_ = (tid & 3) * 8;      // 0,8,16,24

    f32x4 acc[4][4];
    #pragma unroll
    for (int i = 0; i < 4; i++)
        #pragma unroll
        for (int j = 0; j < 4; j++){
            f32x4 z = {0.f, 0.f, 0.f, 0.f};
            acc[i][j] = z;
        }

    for (int k0 = 0; k0 < K; k0 += 32){
        __syncthreads();
        gld16(&Bw[(size_t)(bcol + sr) * K + k0 + sc_],      &Bs[w * 512]);
        gld16(&A [(size_t)(brow + sr) * K + k0 + sc_],      &As[w * 512]);
        gld16(&Bw[(size_t)(bcol + sr + 64) * K + k0 + sc_], &Bs[2048 + w * 512]);
        gld16(&A [(size_t)(brow + sr + 64) * K + k0 + sc_], &As[2048 + w * 512]);
        __syncthreads();
        bf16x8 fb[4];
        #pragma unroll
        for (int j = 0; j < 4; j++){
            int row = wc * 64 + j * 16 + l15;
            fb[j] = *(const bf16x8*)&Bs[row * 32 + 8 * g];
        }
        #pragma unroll
        for (int i = 0; i < 4; i++){
            int row = wr * 64 + i * 16 + l15;
            bf16x8 fa = *(const bf16x8*)&As[row * 32 + 8 * g];
            #pragma unroll
            for (int j = 0; j < 4; j++) acc[i][j] = MFMA(fa, fb[j], acc[i][j]);
        }
        if (SPLIT){
            __syncthreads();
            gld16(&A2[(size_t)(brow + sr) * K + k0 + sc_],      &As[w * 512]);
            gld16(&A2[(size_t)(brow + sr + 64) * K + k0 + sc_], &As[2048 + w * 512]);
            __syncthreads();
            #pragma unroll
            for (int i = 0; i < 4; i++){
                int row = wr * 64 + i * 16 + l15;
                bf16x8 fa = *(const bf16x8*)&As[row * 32 + 8 * g];
                #pragma unroll
                for (int j = 0; j < 4; j++) acc[i][j] = MFMA(fa, fb[j], acc[i][j]);
            }
        }
    }

    #pragma unroll
    for (int i = 0; i < 4; i++){
        #pragma unroll
        for (int j = 0; j < 4; j++){
            int colg = bcol + wc * 64 + j * 16 + l15;
            #pragma unroll
            for (int r = 0; r < 4; r++){
                int rowg = brow + wr * 64 + i * 16 + 4 * g + r;
                float v = acc[i][j][r];
                if (OUTBF) outb[(size_t)rowg * N + colg] = f2bf(v);
                else       outf[(size_t)rowg * N + colg] = v + bias[colg];
            }
        }
    }
}

// ---------------- RMSNorm + RoPE + transpose to (B,H,N,D) ----------------
__global__ __launch_bounds__(256) void k_norm_rope(
    const u16* __restrict__ qkv, const float* __restrict__ qw, const float* __restrict__ kw,
    const float* __restrict__ cosb, const float* __restrict__ sinb,
    u16* __restrict__ qout, u16* __restrict__ kout, u16* __restrict__ vout)
{
    const int m = blockIdx.x;           // 0..4095  (b*N + n)
    const int b = m >> 11;
    const int n = m & 2047;
    const int t = threadIdx.x;
    const size_t base = (size_t)m * FF;
    const int e0 = t * 8;

    float qv[8], kvv[8];
    uint4 qa = *(const uint4*)&qkv[base + e0];
    uint4 ka = *(const uint4*)&qkv[base + CC + e0];
    uint4 va = *(const uint4*)&qkv[base + 2 * CC + e0];
    {
        u32 aa[4] = {qa.x, qa.y, qa.z, qa.w};
        u32 bb[4] = {ka.x, ka.y, ka.z, ka.w};
        #pragma unroll
        for (int i = 0; i < 4; i++){
            qv[2*i]   = bf2f((u16)(aa[i] & 0xffff));
            qv[2*i+1] = bf2f((u16)(aa[i] >> 16));
            kvv[2*i]   = bf2f((u16)(bb[i] & 0xffff));
            kvv[2*i+1] = bf2f((u16)(bb[i] >> 16));
        }
    }
    float sq = 0.f, sk = 0.f;
    #pragma unroll
    for (int i = 0; i < 8; i++){ sq += qv[i]*qv[i]; sk += kvv[i]*kvv[i]; }
    #pragma unroll
    for (int o = 32; o > 0; o >>= 1){ sq += __shfl_xor(sq, o); sk += __shfl_xor(sk, o); }
    __shared__ float red[8];
    if ((t & 63) == 0){ red[(t >> 6)*2] = sq; red[(t >> 6)*2 + 1] = sk; }
    __syncthreads();
    sq = red[0] + red[2] + red[4] + red[6];
    sk = red[1] + red[3] + red[5] + red[7];
    const float rq = rsqrtf(sq * (1.f / 2048.f) + 1e-5f);
    const float rk = rsqrtf(sk * (1.f / 2048.f) + 1e-5f);

    const int h  = t >> 4;
    const int d0 = (t & 15) * 8;
    const float* cp = cosb + (size_t)n * DD + d0;
    const float* sp = sinb + (size_t)n * DD + d0;
    float qo[8], ko[8];
    #pragma unroll
    for (int j = 0; j < 8; j += 2){
        float c0 = cp[j], c1 = cp[j+1], s0 = sp[j], s1 = sp[j+1];
        float x0 = qv[j]   * rq * qw[e0 + j];
        float x1 = qv[j+1] * rq * qw[e0 + j + 1];
        qo[j]   = x0 * c0 - x1 * s0;
        qo[j+1] = x1 * c1 + x0 * s1;
        float y0 = kvv[j]   * rk * kw[e0 + j];
        float y1 = kvv[j+1] * rk * kw[e0 + j + 1];
        ko[j]   = y0 * c0 - y1 * s0;
        ko[j+1] = y1 * c1 + y0 * s1;
    }
    const size_t obase = ((size_t)(b * HH + h) * NN + n) * DD + d0;
    uint4 pq, pk;
    pq.x = (u32)f2bf(qo[0]) | ((u32)f2bf(qo[1]) << 16);
    pq.y = (u32)f2bf(qo[2]) | ((u32)f2bf(qo[3]) << 16);
    pq.z = (u32)f2bf(qo[4]) | ((u32)f2bf(qo[5]) << 16);
    pq.w = (u32)f2bf(qo[6]) | ((u32)f2bf(qo[7]) << 16);
    pk.x = (u32)f2bf(ko[0]) | ((u32)f2bf(ko[1]) << 16);
    pk.y = (u32)f2bf(ko[2]) | ((u32)f2bf(ko[3]) << 16);
    pk.z = (u32)f2bf(ko[4]) | ((u32)f2bf(ko[5]) << 16);
    pk.w = (u32)f2bf(ko[6]) | ((u32)f2bf(ko[7]) << 16);
    *(uint4*)&qout[obase] = pq;
    *(uint4*)&kout[obase] = pk;
    *(uint4*)&vout[obase] = va;   // v: pass-through (already bf16)
}

// ---------------- V transpose: (BH, N, D) -> (BH, D, N) ----------------
__global__ __launch_bounds__(256) void k_vtrans(const u16* __restrict__ V, u16* __restrict__ Vt){
    __shared__ u16 t[64 * 66];   // stride 66: 2-way (free) bank aliasing both phases
    const int bh = blockIdx.z;
    const int n0 = blockIdx.x * 64, d0 = blockIdx.y * 64;
    const int tid = threadIdx.x;
    const int q = tid & 7, p = tid >> 3;   // p: 0..31
    #pragma unroll
    for (int it = 0; it < 2; it++){
        int r = p + it * 32;               // n_rel
        const u16* src = V + ((size_t)bh * NN + n0 + r) * DD + d0 + q * 8;
        uint4 v = *(const uint4*)src;
        u32* dst = (u32*)&t[r * 66 + q * 8];
        dst[0] = v.x; dst[1] = v.y; dst[2] = v.z; dst[3] = v.w;
    }
    __syncthreads();
    #pragma unroll
    for (int it = 0; it < 2; it++){
        int rd = p + it * 32;              // d_rel
        u16 o[8];
        #pragma unroll
        for (int j = 0; j < 8; j++) o[j] = t[(q * 8 + j) * 66 + rd];
        *(uint4*)(Vt + ((size_t)bh * DD + d0 + rd) * NN + n0 + q * 8) = *(uint4*)o;
    }
}

// ---------------- attention v2: 4 waves/block, 32 q-rows/wave, V transposed ----------------
__global__ __launch_bounds__(256) void k_attn2(
    const u16* __restrict__ Q, const u16* __restrict__ Kt, const u16* __restrict__ Vt2,
    u16* __restrict__ O)
{
    const int w = threadIdx.x >> 6, lane = threadIdx.x & 63;
    const int l15 = lane & 15, g = lane >> 4;
    const int qt = blockIdx.x * 4 + w;      // 0..63, 32 q-rows each
    const int h  = blockIdx.y;
    const int b  = blockIdx.z;
    const size_t hb  = (size_t)(b * HH + h) * NN * DD;  // Q, K: (N,D)
    const size_t hbT = (size_t)(b * HH + h) * DD * NN;  // Vt2: (D,N)
    const int qbase = qt * 32;
    const float sc = 0.08838834764831845f * 1.4426950408889634f; // D^-0.5 * log2(e)

    // Q fragments (B operand of S^T = K * Q^T): col = qi = l15, k=d = 32c+8g+j
    bf16x8 qf[2][4];
    #pragma unroll
    for (int u = 0; u < 2; u++){
        const u16* qrow = Q + hb + (size_t)(qbase + u * 16 + l15) * DD;
        #pragma unroll
        for (int c = 0; c < 4; c++)
            qf[u][c] = *(const bf16x8*)(qrow + c * 32 + 8 * g);
    }

    f32x4 oacc[2][8];
    #pragma unroll
    for (int u = 0; u < 2; u++)
        #pragma unroll
        for (int tb = 0; tb < 8; tb++){ f32x4 z = {0.f,0.f,0.f,0.f}; oacc[u][tb] = z; }
    float lsum0 = 0.f, lsum1 = 0.f;

    // kj-interleave: tile0 rows kj=8*(m>>2)+(m&3), tile1 +4 -> lane's C-regs = contiguous kj 8g..8g+7
    const int mperm = 8 * (l15 >> 2) + (l15 & 3);

    for (int kv0 = 0; kv0 < NN; kv0 += 32){
        const u16* k0row = Kt + hb + (size_t)(kv0 + mperm) * DD;
        const u16* k1row = k0row + 4 * DD;
        f32x4 st00 = {0,0,0,0}, st01 = {0,0,0,0}, st10 = {0,0,0,0}, st11 = {0,0,0,0};
        #pragma unroll
        for (int c = 0; c < 4; c++){
            bf16x8 kf0 = *(const bf16x8*)(k0row + c * 32 + 8 * g);
            bf16x8 kf1 = *(const bf16x8*)(k1row + c * 32 + 8 * g);
            st00 = MFMA(kf0, qf[0][c], st00);
            st01 = MFMA(kf0, qf[1][c], st01);
            st10 = MFMA(kf1, qf[0][c], st10);
            st11 = MFMA(kf1, qf[1][c], st11);
        }
        u16x8 pu0, pu1;
        #pragma unroll
        for (int r = 0; r < 4; r++){
            u16 a0 = f2bf(exp2f(st00[r] * sc));
            u16 a1 = f2bf(exp2f(st10[r] * sc));
            pu0[r] = a0; pu0[r + 4] = a1;
            lsum0 += bf2f(a0) + bf2f(a1);
            u16 b0 = f2bf(exp2f(st01[r] * sc));
            u16 b1 = f2bf(exp2f(st11[r] * sc));
            pu1[r] = b0; pu1[r + 4] = b1;
            lsum1 += bf2f(b0) + bf2f(b1);
        }
        bf16x8 pf0 = __builtin_bit_cast(bf16x8, pu0);
        bf16x8 pf1 = __builtin_bit_cast(bf16x8, pu1);
        #pragma unroll
        for (int tb = 0; tb < 8; tb++){
            bf16x8 vf = *(const bf16x8*)(Vt2 + hbT + (size_t)(tb * 16 + l15) * NN + kv0 + 8 * g);
            oacc[0][tb] = MFMA(pf0, vf, oacc[0][tb]);
            oacc[1][tb] = MFMA(pf1, vf, oacc[1][tb]);
        }
    }

    lsum0 += __shfl_xor(lsum0, 16); lsum0 += __shfl_xor(lsum0, 32);
    lsum1 += __shfl_xor(lsum1, 16); lsum1 += __shfl_xor(lsum1, 32);
    float linv0 = 1.f / lsum0, linv1 = 1.f / lsum1;
    float li0[4], li1[4];
    #pragma unroll
    for (int r = 0; r < 4; r++){
        li0[r] = __shfl(linv0, 4 * g + r);
        li1[r] = __shfl(linv1, 4 * g + r);
    }

    #pragma unroll
    for (int tb = 0; tb < 8; tb++){
        #pragma unroll
        for (int r = 0; r < 4; r++){
            int q0 = qbase + 4 * g + r;
            O[(size_t)(b * NN + q0) * CC + h * DD + tb * 16 + l15] = f2bf(oacc[0][tb][r] * li0[r]);
            int q1 = qbase + 16 + 4 * g + r;
            O[(size_t)(b * NN + q1) * CC + h * DD + tb * 16 + l15] = f2bf(oacc[1][tb][r] * li1[r]);
        }
    }
}

// ---------------- launch ----------------
extern "C" void kernel_launch(void* const* d_in, const int* in_sizes, int n_in,
                              void* d_out, int out_size, void* d_ws, size_t ws_size,
                              hipStream_t stream) {
    const float* x      = (const float*)d_in[0];
    const float* w_qkv  = (const float*)d_in[1];
    const float* qw     = (const float*)d_in[2];
    const float* kw     = (const float*)d_in[3];
    const float* cosb   = (const float*)d_in[4];
    const float* sinb   = (const float*)d_in[5];
    const float* w_proj = (const float*)d_in[6];
    const float* b_proj = (const float*)d_in[7];
    float* out = (float*)d_out;

    const size_t sz_xhi  = (size_t)MM * CC * 2;        // 16 MiB
    const size_t sz_wqkv = (size_t)FF * CC * 2;        // 24 MiB
    const size_t sz_wprj = (size_t)CC * CC * 2;        // 8 MiB
    const size_t sz_qkv  = (size_t)MM * FF * 2;        // 48 MiB
    const size_t sz_t    = (size_t)BB * HH * NN * DD * 2; // 16 MiB each
    const size_t need = sz_xhi*2 + sz_wqkv + sz_wprj + sz_qkv + sz_t*3 + sz_xhi;
    if (ws_size < need) return;

    char* ws = (char*)d_ws;
    size_t off = 0;
    auto alloc = [&](size_t bytes){ void* p = ws + off; off += (bytes + 255) & ~(size_t)255; return p; };
    u16* x_hi    = (u16*)alloc(sz_xhi);
    u16* x_lo    = (u16*)alloc(sz_xhi);
    u16* wqkv_bf = (u16*)alloc(sz_wqkv);
    u16* wprj_bf = (u16*)alloc(sz_wprj);
    u16* qkv     = (u16*)alloc(sz_qkv);
    u16* qr      = (u16*)alloc(sz_t);
    u16* kr      = (u16*)alloc(sz_t);
    u16* vt      = (u16*)alloc(sz_t);
    u16* ob      = (u16*)alloc(sz_xhi);
    u16* vt2     = qkv;   // qkv is dead after k_norm_rope; reuse for transposed V

    k_split_x<<<2048, 256, 0, stream>>>(x, x_hi, x_lo, MM * CC / 4);
    k_f2bf<<<2048, 256, 0, stream>>>(w_qkv, wqkv_bf, FF * CC / 4);
    k_f2bf<<<1024, 256, 0, stream>>>(w_proj, wprj_bf, CC * CC / 4);
    k_gemm_bt<1, 1><<<dim3(FF / 128, MM / 128), 256, 0, stream>>>(
        x_hi, x_lo, wqkv_bf, nullptr, qkv, nullptr, MM, FF, CC);
    k_norm_rope<<<MM, 256, 0, stream>>>(qkv, qw, kw, cosb, sinb, qr, kr, vt);
    k_vtrans<<<dim3(NN / 64, DD / 64, BB * HH), 256, 0, stream>>>(vt, vt2);
    k_attn2<<<dim3(16, HH, BB), 256, 0, stream>>>(qr, kr, vt2, ob);
    k_gemm_bt<0, 0><<<dim3(CC / 128, MM / 128), 256, 0, stream>>>(
        ob, nullptr, wprj_bf, out, nullptr, b_proj, MM, CC, CC);
}